// Round 10
// baseline (168.866 us; speedup 1.0000x reference)
//
#include <hip/hip_runtime.h>

typedef __bf16 bf16x8 __attribute__((ext_vector_type(8)));
typedef float  f32x4  __attribute__((ext_vector_type(4)));

#define CC 64
#define HWSZ 4096
#define CHWSZ 262144
#define NE 512
#define NPIX 131072
#define PIXB 64
#define EPS_MARGIN 0.01f
#define NSTRIPE 32

#define ET_OFF 0              // 512 codes * 256 B (hi64|lo64 bf16), LINEAR rows
#define E2_OFF 131072         // 512 * 4
#define HIST_OFF 133120       // 32 stripes * 512 * 4 = 65536
#define BATCH_OFF 198656      // 32 * 4
#define IDX_OFF 198784        // 131072 * 2 (u16)

__device__ __forceinline__ float bf2f(unsigned short u) {
    unsigned int x = ((unsigned int)u) << 16;
    return __builtin_bit_cast(float, x);
}
__device__ __forceinline__ unsigned short f2bf(float f) {
    unsigned int x = __builtin_bit_cast(unsigned int, f);
    unsigned int r = x + 0x7fffu + ((x >> 16) & 1u);
    return (unsigned short)(r >> 16);
}

// ---- init (8 blocks): exact e2[512]; embed^T hi/lo [code][hi64|lo64] bf16 LINEAR ----
__global__ __launch_bounds__(512) void vq_init(const float* __restrict__ eg, char* __restrict__ ws) {
    const int tid = threadIdx.x, blk = blockIdx.x;
    if (tid < 64) {
        int n = blk * 64 + tid;
        float s = 0.f;
        #pragma unroll 8
        for (int k = 0; k < CC; ++k) { float v = eg[k * NE + n]; s = __fadd_rn(s, __fmul_rn(v, v)); }
        ((float*)(ws + E2_OFF))[n] = s;
    }
    unsigned int* et32 = (unsigned int*)(ws + ET_OFF);
    #pragma unroll
    for (int it = 0; it < 8; ++it) {
        int idx = blk * 4096 + it * 512 + tid;   // global word index
        int n = idx >> 6, w = idx & 63;
        int k = (w & 31) << 1;
        float v0 = eg[k * NE + n], v1 = eg[(k + 1) * NE + n];
        unsigned short c0, c1;
        if (w < 32) { c0 = f2bf(v0); c1 = f2bf(v1); }
        else {
            unsigned short h0 = f2bf(v0), h1 = f2bf(v1);
            c0 = f2bf(__fsub_rn(v0, bf2f(h0)));
            c1 = f2bf(__fsub_rn(v1, bf2f(h1)));
        }
        et32[idx] = (unsigned int)c0 | ((unsigned int)c1 << 16);
    }
    unsigned int* h32 = (unsigned int*)(ws + HIST_OFF);
    for (int i = blk * 2048 + tid; i < (blk + 1) * 2048; i += 512) h32[i] = 0u;
    if (blk == 0 && tid < 32) ((float*)(ws + BATCH_OFF))[tid] = 0.f;
}

// ---- K1: code-partitioned barrier-free screen ----
// Block = 64 pixels, 4 waves; wave w owns codes [w*128, w*128+128) for ALL 64 pixels.
// B-fragments gathered from L2-hot linear et into registers, 2-deep pipelined.
__global__ __launch_bounds__(256) void vq_argmin(const float* __restrict__ xg,
                                                 const float* __restrict__ eg,
                                                 char* __restrict__ ws) {
    __shared__ __align__(16) char xtb[PIXB * 256];  // [pixel][hi64|lo64] bf16, XOR-swizzled
    __shared__ float e2s[NE];
    __shared__ float cmin[4][PIXB];
    __shared__ float cmin2[4][PIXB];
    __shared__ int   cidx[4][PIXB];
    __shared__ float xp[4][CC];

    const int tid  = threadIdx.x;
    const int lane = tid & 63;
    const int wv   = tid >> 6;
    const int l15  = lane & 15;
    const int l4   = lane >> 4;
    const int pix0 = blockIdx.x * PIXB;
    const int bb   = pix0 >> 12;
    const size_t xbase = (size_t)bb * CHWSZ + (pix0 & 4095);
    const char* etw = ws + ET_OFF;

    // stage x tile (64 pixels) as bf16 hi/lo, swizzled; stage e2s
    {
        const int p = tid & 63, h = tid >> 6;
        const int sw = (p & 15) << 4;
        #pragma unroll
        for (int q = 0; q < 2; ++q) {
            int k0 = h * 16 + q * 8;
            float v[8];
            #pragma unroll
            for (int j = 0; j < 8; ++j) v[j] = xg[xbase + (size_t)(k0 + j) * HWSZ + p];
            unsigned int hw_[4], lw_[4];
            #pragma unroll
            for (int j = 0; j < 4; ++j) {
                unsigned short h0 = f2bf(v[2 * j]), h1 = f2bf(v[2 * j + 1]);
                unsigned short o0 = f2bf(__fsub_rn(v[2 * j], bf2f(h0)));
                unsigned short o1 = f2bf(__fsub_rn(v[2 * j + 1], bf2f(h1)));
                hw_[j] = (unsigned int)h0 | ((unsigned int)h1 << 16);
                lw_[j] = (unsigned int)o0 | ((unsigned int)o1 << 16);
            }
            *(uint4*)(xtb + ((p * 256 + 2 * k0) ^ sw)) = (uint4){hw_[0], hw_[1], hw_[2], hw_[3]};
            *(uint4*)(xtb + ((p * 256 + 128 + 2 * k0) ^ sw)) = (uint4){lw_[0], lw_[1], lw_[2], lw_[3]};
        }
        const float* e2g = (const float*)(ws + E2_OFF);
        for (int t = tid; t < NE; t += 256) e2s[t] = e2g[t];
    }
    __syncthreads();

    // A fragments (hi, lo): 4 m-tiles = all 64 pixels
    bf16x8 ah[4][2], al[4][2];
    #pragma unroll
    for (int mt = 0; mt < 4; ++mt) {
        int prow = mt * 16 + l15;
        int sw = (prow & 15) << 4;
        #pragma unroll
        for (int kh = 0; kh < 2; ++kh) {
            ah[mt][kh] = *(const bf16x8*)(xtb + ((prow * 256 + kh * 64 + l4 * 16) ^ sw));
            al[mt][kh] = *(const bf16x8*)(xtb + ((prow * 256 + 128 + kh * 64 + l4 * 16) ^ sw));
        }
    }

    float minv[4][4], min2v[4][4];
    int   mini[4][4];
    #pragma unroll
    for (int mt = 0; mt < 4; ++mt)
        #pragma unroll
        for (int r = 0; r < 4; ++r) { minv[mt][r] = 3.4e38f; min2v[mt][r] = 3.4e38f; mini[mt][r] = 0; }

    // per-lane B gather base for this wave's code range
    const char* bpbase = etw + ((size_t)(wv * 128 + l15) << 8) + (l4 << 4);

    bf16x8 b0h0, b0h1, b0l0, b0l1, b1h0, b1h1, b1l0, b1l1;

#define LOADB0(g) { const char* bp_ = bpbase + (g) * 4096; \
    b0h0 = *(const bf16x8*)(bp_);       b0h1 = *(const bf16x8*)(bp_ + 64); \
    b0l0 = *(const bf16x8*)(bp_ + 128); b0l1 = *(const bf16x8*)(bp_ + 192); }
#define LOADB1(g) { const char* bp_ = bpbase + (g) * 4096; \
    b1h0 = *(const bf16x8*)(bp_);       b1h1 = *(const bf16x8*)(bp_ + 64); \
    b1l0 = *(const bf16x8*)(bp_ + 128); b1l1 = *(const bf16x8*)(bp_ + 192); }
#define COMPUTE(BH0, BH1, BL0, BL1, g) { \
    const int code = wv * 128 + (g) * 16 + l15; \
    const float e2v = e2s[code]; \
    _Pragma("unroll") \
    for (int mt = 0; mt < 4; ++mt) { \
        f32x4 acc = (f32x4){0.f, 0.f, 0.f, 0.f}; \
        acc = __builtin_amdgcn_mfma_f32_16x16x32_bf16(ah[mt][0], BH0, acc, 0, 0, 0); \
        acc = __builtin_amdgcn_mfma_f32_16x16x32_bf16(ah[mt][1], BH1, acc, 0, 0, 0); \
        acc = __builtin_amdgcn_mfma_f32_16x16x32_bf16(ah[mt][0], BL0, acc, 0, 0, 0); \
        acc = __builtin_amdgcn_mfma_f32_16x16x32_bf16(ah[mt][1], BL1, acc, 0, 0, 0); \
        acc = __builtin_amdgcn_mfma_f32_16x16x32_bf16(al[mt][0], BH0, acc, 0, 0, 0); \
        acc = __builtin_amdgcn_mfma_f32_16x16x32_bf16(al[mt][1], BH1, acc, 0, 0, 0); \
        _Pragma("unroll") \
        for (int r2 = 0; r2 < 4; ++r2) { \
            float d = __fmaf_rn(-2.f, acc[r2], e2v); \
            bool lt = d < minv[mt][r2]; \
            min2v[mt][r2] = fminf(min2v[mt][r2], fmaxf(d, minv[mt][r2])); \
            minv[mt][r2] = lt ? d : minv[mt][r2]; \
            mini[mt][r2] = lt ? code : mini[mt][r2]; \
        } } }

    LOADB0(0);
    LOADB1(1);
    #pragma unroll
    for (int g = 0; g < 8; g += 2) {
        COMPUTE(b0h0, b0h1, b0l0, b0l1, g);
        if (g + 2 < 8) LOADB0(g + 2);
        COMPUTE(b1h0, b1h1, b1l0, b1l1, g + 1);
        if (g + 3 < 8) LOADB1(g + 3);
    }
#undef LOADB0
#undef LOADB1
#undef COMPUTE

    // 16-lane argmin reduce (within wave's code range), second-min + first-index tie-break
    #pragma unroll
    for (int m = 1; m < 16; m <<= 1) {
        #pragma unroll
        for (int mt = 0; mt < 4; ++mt)
            #pragma unroll
            for (int r = 0; r < 4; ++r) {
                float ov  = __shfl_xor(minv[mt][r], m, 64);
                int   oi  = __shfl_xor(mini[mt][r], m, 64);
                float ov2 = __shfl_xor(min2v[mt][r], m, 64);
                bool sel = (ov < minv[mt][r]) || (ov == minv[mt][r] && oi < mini[mt][r]);
                float big = sel ? minv[mt][r] : ov;
                min2v[mt][r] = fminf(fminf(min2v[mt][r], ov2), big);
                minv[mt][r] = sel ? ov : minv[mt][r];
                mini[mt][r] = sel ? oi : mini[mt][r];
            }
    }
    // publish this wave's per-pixel triples
    if (l15 == 0) {
        #pragma unroll
        for (int mt = 0; mt < 4; ++mt)
            #pragma unroll
            for (int r = 0; r < 4; ++r) {
                int p = mt * 16 + l4 * 4 + r;
                cmin[wv][p] = minv[mt][r];
                cmin2[wv][p] = min2v[mt][r];
                cidx[wv][p] = mini[mt][r];
            }
    }
    __syncthreads();

    // cross-wave combine (every lane handles pixel = lane; waves ascending = codes ascending)
    float gm = cmin[0][lane], gs = cmin2[0][lane];
    int   gi = cidx[0][lane];
    #pragma unroll
    for (int w2 = 1; w2 < 4; ++w2) {
        float m2 = cmin[w2][lane], s2 = cmin2[w2][lane];
        int   i2 = cidx[w2][lane];
        if (m2 < gm) { gs = fminf(fminf(gm, s2), gs); gm = m2; gi = i2; }
        else         { gs = fminf(gs, m2); }
    }
    bool flag = (gs - gm < EPS_MARGIN);

    // per-wave exact recheck: wave w owns pixels [16w, 16w+16) — bit-identical fp32 arithmetic
    {
        unsigned long long mask = __ballot(flag) & (0xFFFFull << (wv * 16));
        while (mask) {
            int p = __ffsll((long long)mask) - 1;
            mask &= mask - 1;
            xp[wv][lane] = xg[xbase + (size_t)lane * HWSZ + p];   // k = lane
            float rr[8];
            #pragma unroll
            for (int u = 0; u < 8; ++u) { float v = xp[wv][u]; rr[u] = __fmul_rn(v, v); }
            #pragma unroll
            for (int t2 = 1; t2 < 8; ++t2)
                #pragma unroll
                for (int u = 0; u < 8; ++u) { float v = xp[wv][t2 * 8 + u]; rr[u] = __fadd_rn(rr[u], __fmul_rn(v, v)); }
            float f2 = __fadd_rn(__fadd_rn(__fadd_rn(rr[0], rr[1]), __fadd_rn(rr[2], rr[3])),
                                 __fadd_rn(__fadd_rn(rr[4], rr[5]), __fadd_rn(rr[6], rr[7])));
            const int c0 = lane * 8;
            float dot[8];
            #pragma unroll
            for (int j = 0; j < 8; ++j) dot[j] = 0.f;
            #pragma unroll 4
            for (int k = 0; k < CC; ++k) {
                float xv = xp[wv][k];
                float4 a = *(const float4*)(eg + k * NE + c0);
                float4 b = *(const float4*)(eg + k * NE + c0 + 4);
                dot[0] = __fmaf_rn(xv, a.x, dot[0]); dot[1] = __fmaf_rn(xv, a.y, dot[1]);
                dot[2] = __fmaf_rn(xv, a.z, dot[2]); dot[3] = __fmaf_rn(xv, a.w, dot[3]);
                dot[4] = __fmaf_rn(xv, b.x, dot[4]); dot[5] = __fmaf_rn(xv, b.y, dot[5]);
                dot[6] = __fmaf_rn(xv, b.z, dot[6]); dot[7] = __fmaf_rn(xv, b.w, dot[7]);
            }
            float best = 3.4e38f; int bidx = 0;
            #pragma unroll
            for (int j = 0; j < 8; ++j) {
                float d = __fadd_rn(__fmaf_rn(-2.f, dot[j], f2), e2s[c0 + j]);
                if (d < best) { best = d; bidx = c0 + j; }
            }
            #pragma unroll
            for (int m = 1; m < 64; m <<= 1) {
                float ov = __shfl_xor(best, m, 64);
                int   oi = __shfl_xor(bidx, m, 64);
                if (ov < best || (ov == best && oi < bidx)) { best = ov; bidx = oi; }
            }
            int nb = __shfl(bidx, 0, 64);
            if (lane == p) gi = nb;
        }
    }

    // write: wave w writes its 16 pixels; striped hist atomics
    if ((lane >> 4) == wv) {
        ((unsigned short*)(ws + IDX_OFF))[pix0 + lane] = (unsigned short)gi;
        atomicAdd((unsigned int*)(ws + HIST_OFF) + (blockIdx.x & (NSTRIPE - 1)) * NE + gi, 1u);
    }
}

// ---- K2: streaming apply — block = one (batch, channel) plane of 4096 pixels ----
__global__ __launch_bounds__(256) void vq_apply(const float* __restrict__ xg,
                                                const float* __restrict__ eg,
                                                float* __restrict__ outg,
                                                char* __restrict__ ws) {
    __shared__ float wsum[4];
    const int tid = threadIdx.x, lane = tid & 63, wv = tid >> 6;
    const int bb = blockIdx.x >> 6;
    const int cc = blockIdx.x & 63;
    const size_t base = (size_t)bb * CHWSZ + (size_t)cc * HWSZ;
    const unsigned short* idxg = (const unsigned short*)(ws + IDX_OFF) + bb * 4096;
    const float* erow = eg + cc * NE;

    float sq = 0.f;
    #pragma unroll
    for (int it = 0; it < 4; ++it) {
        int p4 = (it * 256 + tid) * 4;
        float4 vr = *(const float4*)(xg + base + p4);
        ushort4 iv = *(const ushort4*)(idxg + p4);
        float q0 = erow[iv.x], q1 = erow[iv.y], q2 = erow[iv.z], q3 = erow[iv.w];
        float vv[4] = {vr.x, vr.y, vr.z, vr.w};
        float qq[4] = {q0, q1, q2, q3};
        float4 ov;
        float* ovp = &ov.x;
        #pragma unroll
        for (int j = 0; j < 4; ++j) {
            float d = __fsub_rn(qq[j], vv[j]);
            ovp[j] = __fadd_rn(vv[j], d);
            sq = __fmaf_rn(d, d, sq);
        }
        *(float4*)(outg + base + p4) = ov;
    }
    #pragma unroll
    for (int m = 32; m >= 1; m >>= 1) sq += __shfl_down(sq, m, 64);
    if (lane == 0) wsum[wv] = sq;
    __syncthreads();
    if (tid == 0) atomicAdd((float*)(ws + BATCH_OFF) + bb, wsum[0] + wsum[1] + wsum[2] + wsum[3]);
}

// ---- finalize: sum hist stripes, diff[32], perplexity ----
__global__ __launch_bounds__(512) void vq_fin(const char* __restrict__ ws, float* __restrict__ outg) {
    __shared__ float acc8[8];
    const int tid = threadIdx.x, lane = tid & 63, wv = tid >> 6;
    const unsigned int* h32 = (const unsigned int*)(ws + HIST_OFF);
    unsigned int h = 0;
    #pragma unroll
    for (int s = 0; s < NSTRIPE; ++s) h += h32[s * NE + tid];
    float p = (float)h * (1.f / (float)NPIX);
    float t = p * logf(p + 1e-10f);
    #pragma unroll
    for (int m = 32; m >= 1; m >>= 1) t += __shfl_down(t, m, 64);
    if (lane == 0) acc8[wv] = t;
    __syncthreads();
    if (tid < 32) outg[8388608 + tid] = ((const float*)(ws + BATCH_OFF))[tid] * (1.f / 262144.f);
    if (tid == 0) {
        float s = 0.f;
        #pragma unroll
        for (int u = 0; u < 8; ++u) s += acc8[u];
        outg[8388640] = expf(-s);
    }
}

extern "C" void kernel_launch(void* const* d_in, const int* in_sizes, int n_in,
                              void* d_out, int out_size, void* d_ws, size_t ws_size,
                              hipStream_t stream) {
    const float* xg = (const float*)d_in[0];
    const float* eg = (const float*)d_in[1];
    float* outg = (float*)d_out;
    char* ws = (char*)d_ws;
    vq_init<<<8, 512, 0, stream>>>(eg, ws);
    vq_argmin<<<NPIX / PIXB, 256, 0, stream>>>(xg, eg, ws);
    vq_apply<<<32 * 64, 256, 0, stream>>>(xg, eg, outg, ws);
    vq_fin<<<1, 512, 0, stream>>>(ws, outg);
}

// Round 11
// 119.347 us; speedup vs baseline: 1.4149x; 1.4149x over previous
//
#include <hip/hip_runtime.h>

typedef __bf16 bf16x8 __attribute__((ext_vector_type(8)));
typedef float  f32x4  __attribute__((ext_vector_type(4)));

#define CC 64
#define HWSZ 4096
#define CHWSZ 262144
#define NE 512
#define NPIX 131072
#define PIXB 128
#define EPS_MARGIN 0.012f
#define NSTRIPE 32

#define ET_OFF 0              // 512 codes * 256 B (hi64|lo64 bf16), XOR-swizzled rows
#define E2_OFF 131072         // 512 * 4
#define HIST_OFF 133120       // 32 stripes * 512 * 4 = 65536
#define BATCH_OFF 198656      // 32 * 4
#define PART_OFF 198784       // 131072 pixels * 4 quarters * 8 B = 4194304

__device__ __forceinline__ float bf2f(unsigned short u) {
    unsigned int x = ((unsigned int)u) << 16;
    return __builtin_bit_cast(float, x);
}
__device__ __forceinline__ unsigned short f2bf(float f) {
    unsigned int x = __builtin_bit_cast(unsigned int, f);
    unsigned int r = x + 0x7fffu + ((x >> 16) & 1u);
    return (unsigned short)(r >> 16);
}
__device__ __forceinline__ void gload16(const void* g, void* l) {
    __builtin_amdgcn_global_load_lds(
        (const __attribute__((address_space(1))) unsigned int*)g,
        (__attribute__((address_space(3))) unsigned int*)l, 16, 0, 0);
}

// ---- init (8 blocks): exact e2[512]; embed^T hi/lo [code][hi64|lo64] bf16 PRE-SWIZZLED ----
__global__ __launch_bounds__(512) void vq_init(const float* __restrict__ eg, char* __restrict__ ws) {
    const int tid = threadIdx.x, blk = blockIdx.x;
    if (tid < 64) {
        int n = blk * 64 + tid;
        float s = 0.f;
        #pragma unroll 8
        for (int k = 0; k < CC; ++k) { float v = eg[k * NE + n]; s = __fadd_rn(s, __fmul_rn(v, v)); }
        ((float*)(ws + E2_OFF))[n] = s;
    }
    char* et = ws + ET_OFF;
    #pragma unroll
    for (int it = 0; it < 8; ++it) {
        int idx = blk * 4096 + it * 512 + tid;   // global word index
        int n = idx >> 6, w = idx & 63;
        int k = (w & 31) << 1;
        float v0 = eg[k * NE + n], v1 = eg[(k + 1) * NE + n];
        unsigned short c0, c1;
        if (w < 32) { c0 = f2bf(v0); c1 = f2bf(v1); }
        else {
            unsigned short h0 = f2bf(v0), h1 = f2bf(v1);
            c0 = f2bf(__fsub_rn(v0, bf2f(h0)));
            c1 = f2bf(__fsub_rn(v1, bf2f(h1)));
        }
        int b = (n * 256 + w * 4) ^ ((n & 15) << 4);   // row-local XOR swizzle (matches reader)
        *(unsigned int*)(et + b) = (unsigned int)c0 | ((unsigned int)c1 << 16);
    }
    unsigned int* h32 = (unsigned int*)(ws + HIST_OFF);
    for (int i = blk * 2048 + tid; i < (blk + 1) * 2048; i += 512) h32[i] = 0u;
    if (blk == 0 && tid < 32) ((float*)(ws + BATCH_OFF))[tid] = 0.f;
}

// ---- K1: code-split screen. Block = 128 pixels x one 128-code quarter; stage once,
// ONE barrier, then every wave free-runs its 2 m-tiles x 8 groups with no sync. ----
__global__ __launch_bounds__(256) void vq_screen(const float* __restrict__ xg,
                                                 char* __restrict__ ws) {
    __shared__ __align__(16) char xtb[PIXB * 256];   // x tile [pixel][hi64|lo64], swizzled
    __shared__ __align__(16) char btb[128 * 256];    // B quarter [code_local][hi64|lo64], swizzled
    __shared__ float e2q[128];

    const int tid  = threadIdx.x;
    const int lane = tid & 63;
    const int wv   = tid >> 6;
    const int l15  = lane & 15;
    const int l4   = lane >> 4;
    const int blk  = blockIdx.x;
    const int tile = blk >> 2;
    const int q    = blk & 3;
    const int pix0 = tile * PIXB;
    const int bb   = pix0 >> 12;
    const size_t xbase = (size_t)bb * CHWSZ + (pix0 & 4095);
    const char* etw = ws + ET_OFF;

    // stage B quarter (pre-swizzled, linear copy): 32KB = 256 thr x 8 x 16B
    #pragma unroll
    for (int i = 0; i < 8; ++i)
        gload16(etw + (size_t)q * 32768 + i * 4096 + tid * 16, &btb[i * 4096 + tid * 16]);

    // stage x tile as bf16 hi/lo, swizzled
    {
        const int p = tid & 127, h = tid >> 7;
        const int sw = (p & 15) << 4;
        #pragma unroll
        for (int qq = 0; qq < 4; ++qq) {
            int k0 = h * 32 + qq * 8;
            float v[8];
            #pragma unroll
            for (int j = 0; j < 8; ++j) v[j] = xg[xbase + (size_t)(k0 + j) * HWSZ + p];
            unsigned int hw_[4], lw_[4];
            #pragma unroll
            for (int j = 0; j < 4; ++j) {
                unsigned short h0 = f2bf(v[2 * j]), h1 = f2bf(v[2 * j + 1]);
                unsigned short o0 = f2bf(__fsub_rn(v[2 * j], bf2f(h0)));
                unsigned short o1 = f2bf(__fsub_rn(v[2 * j + 1], bf2f(h1)));
                hw_[j] = (unsigned int)h0 | ((unsigned int)h1 << 16);
                lw_[j] = (unsigned int)o0 | ((unsigned int)o1 << 16);
            }
            *(uint4*)(xtb + ((p * 256 + 2 * k0) ^ sw)) = (uint4){hw_[0], hw_[1], hw_[2], hw_[3]};
            *(uint4*)(xtb + ((p * 256 + 128 + 2 * k0) ^ sw)) = (uint4){lw_[0], lw_[1], lw_[2], lw_[3]};
        }
        if (tid < 128) e2q[tid] = ((const float*)(ws + E2_OFF))[q * 128 + tid];
    }
    asm volatile("s_waitcnt vmcnt(0) lgkmcnt(0)" ::: "memory");
    __syncthreads();       // the ONLY barrier

    // A fragments (hi, lo): wave owns pixels [32wv, 32wv+32) = 2 m-tiles
    bf16x8 ah[2][2], al[2][2];
    #pragma unroll
    for (int mt = 0; mt < 2; ++mt) {
        int prow = (2 * wv + mt) * 16 + l15;
        int sw = (prow & 15) << 4;
        #pragma unroll
        for (int kh = 0; kh < 2; ++kh) {
            ah[mt][kh] = *(const bf16x8*)(xtb + ((prow * 256 + kh * 64 + l4 * 16) ^ sw));
            al[mt][kh] = *(const bf16x8*)(xtb + ((prow * 256 + 128 + kh * 64 + l4 * 16) ^ sw));
        }
    }

    float minv[2][4], min2v[2][4];
    int   mini[2][4];
    #pragma unroll
    for (int mt = 0; mt < 2; ++mt)
        #pragma unroll
        for (int r = 0; r < 4; ++r) { minv[mt][r] = 3.4e38f; min2v[mt][r] = 3.4e38f; mini[mt][r] = 0; }

    // free-run: 8 groups x 16 codes, fully unrolled, no sync
    #pragma unroll
    for (int g = 0; g < 8; ++g) {
        const int r = g * 16 + l15;
        const int code = q * 128 + r;
        const int ro = r * 256 + l4 * 16;
        const int sw2 = (r & 15) << 4;
        bf16x8 bh0 = *(const bf16x8*)(btb + ((ro +   0) ^ sw2));
        bf16x8 bh1 = *(const bf16x8*)(btb + ((ro +  64) ^ sw2));
        bf16x8 bl0 = *(const bf16x8*)(btb + ((ro + 128) ^ sw2));
        bf16x8 bl1 = *(const bf16x8*)(btb + ((ro + 192) ^ sw2));
        float e2v = e2q[r];
        #pragma unroll
        for (int mt = 0; mt < 2; ++mt) {
            f32x4 acc = (f32x4){0.f, 0.f, 0.f, 0.f};
            acc = __builtin_amdgcn_mfma_f32_16x16x32_bf16(ah[mt][0], bh0, acc, 0, 0, 0);
            acc = __builtin_amdgcn_mfma_f32_16x16x32_bf16(ah[mt][1], bh1, acc, 0, 0, 0);
            acc = __builtin_amdgcn_mfma_f32_16x16x32_bf16(ah[mt][0], bl0, acc, 0, 0, 0);
            acc = __builtin_amdgcn_mfma_f32_16x16x32_bf16(ah[mt][1], bl1, acc, 0, 0, 0);
            acc = __builtin_amdgcn_mfma_f32_16x16x32_bf16(al[mt][0], bh0, acc, 0, 0, 0);
            acc = __builtin_amdgcn_mfma_f32_16x16x32_bf16(al[mt][1], bh1, acc, 0, 0, 0);
            #pragma unroll
            for (int r2 = 0; r2 < 4; ++r2) {
                float d = __fmaf_rn(-2.f, acc[r2], e2v);
                bool lt = d < minv[mt][r2];
                min2v[mt][r2] = fminf(min2v[mt][r2], fmaxf(d, minv[mt][r2]));
                minv[mt][r2] = lt ? d : minv[mt][r2];
                mini[mt][r2] = lt ? code : mini[mt][r2];
            }
        }
    }

    // 16-lane argmin reduce with second-min + first-index tie-break
    #pragma unroll
    for (int m = 1; m < 16; m <<= 1) {
        #pragma unroll
        for (int mt = 0; mt < 2; ++mt)
            #pragma unroll
            for (int r = 0; r < 4; ++r) {
                float ov  = __shfl_xor(minv[mt][r], m, 64);
                int   oi  = __shfl_xor(mini[mt][r], m, 64);
                float ov2 = __shfl_xor(min2v[mt][r], m, 64);
                bool sel = (ov < minv[mt][r]) || (ov == minv[mt][r] && oi < mini[mt][r]);
                float big = sel ? minv[mt][r] : ov;
                min2v[mt][r] = fminf(fminf(min2v[mt][r], ov2), big);
                minv[mt][r] = sel ? ov : minv[mt][r];
                mini[mt][r] = sel ? oi : mini[mt][r];
            }
    }

    // packed partial per pixel: {hi: min f32 bits, lo: idx u16 | margin f16 << 16}
    if (l15 == 0) {
        uint2* part = (uint2*)(ws + PART_OFF);
        #pragma unroll
        for (int mt = 0; mt < 2; ++mt)
            #pragma unroll
            for (int r = 0; r < 4; ++r) {
                int p = wv * 32 + mt * 16 + l4 * 4 + r;
                float margin = min2v[mt][r] - minv[mt][r];
                _Float16 mh = (_Float16)margin;
                unsigned int lo = (unsigned int)mini[mt][r]
                                | ((unsigned int)__builtin_bit_cast(unsigned short, mh) << 16);
                unsigned int hi = __builtin_bit_cast(unsigned int, minv[mt][r]);
                part[(size_t)(pix0 + p) * 4 + q] = (uint2){lo, hi};
            }
    }
}

// ---- K2: combine quarters + exact recheck + apply + hist + sq ----
__global__ __launch_bounds__(256) void vq_apply(const float* __restrict__ xg,
                                                const float* __restrict__ eg,
                                                float* __restrict__ outg,
                                                char* __restrict__ ws) {
    __shared__ int idxs[PIXB];
    __shared__ unsigned char flg[PIXB];
    __shared__ float e2s[NE];
    __shared__ float xp[4][CC];
    __shared__ float wsum[4];

    const int tid  = threadIdx.x;
    const int lane = tid & 63;
    const int wv   = tid >> 6;
    const int pix0 = blockIdx.x * PIXB;
    const int bb   = pix0 >> 12;
    const size_t xbase = (size_t)bb * CHWSZ + (pix0 & 4095);

    // stage e2 (for recheck)
    {
        const float* e2g = (const float*)(ws + E2_OFF);
        for (int t = tid; t < NE; t += 256) e2s[t] = e2g[t];
    }

    // combine 4 quarters per pixel
    if (tid < PIXB) {
        const uint2* part = (const uint2*)(ws + PART_OFF) + (size_t)(pix0 + tid) * 4;
        float g1 = 3.4e38f, g2 = 3.4e38f;
        int gi = 0;
        #pragma unroll
        for (int q = 0; q < 4; ++q) {
            uint2 pa = part[q];
            float m = __builtin_bit_cast(float, pa.y);
            int idx = (int)(pa.x & 0xffffu);
            _Float16 mh = __builtin_bit_cast(_Float16, (unsigned short)(pa.x >> 16));
            float m2 = m + (float)mh;
            if (m < g1) { g2 = fminf(g1, m2); g1 = m; gi = idx; }
            else        { g2 = fminf(g2, m); }
        }
        idxs[tid] = gi;
        flg[tid] = (g2 - g1 < EPS_MARGIN) ? 1 : 0;
    }
    __syncthreads();

    // per-wave exact recheck: wave wv owns pixels [32wv, 32wv+32)
    {
        bool f = (lane < 32) ? (flg[wv * 32 + lane] != 0) : false;
        unsigned long long mask = __ballot(f);
        while (mask) {
            int l0 = __ffsll((long long)mask) - 1;
            mask &= mask - 1;
            int p = wv * 32 + l0;
            xp[wv][lane] = xg[xbase + (size_t)lane * HWSZ + p];   // k = lane
            float rr[8];
            #pragma unroll
            for (int u = 0; u < 8; ++u) { float v = xp[wv][u]; rr[u] = __fmul_rn(v, v); }
            #pragma unroll
            for (int t2 = 1; t2 < 8; ++t2)
                #pragma unroll
                for (int u = 0; u < 8; ++u) { float v = xp[wv][t2 * 8 + u]; rr[u] = __fadd_rn(rr[u], __fmul_rn(v, v)); }
            float f2 = __fadd_rn(__fadd_rn(__fadd_rn(rr[0], rr[1]), __fadd_rn(rr[2], rr[3])),
                                 __fadd_rn(__fadd_rn(rr[4], rr[5]), __fadd_rn(rr[6], rr[7])));
            const int c0 = lane * 8;
            float dot[8];
            #pragma unroll
            for (int j = 0; j < 8; ++j) dot[j] = 0.f;
            #pragma unroll 4
            for (int k = 0; k < CC; ++k) {
                float xv = xp[wv][k];
                float4 a = *(const float4*)(eg + k * NE + c0);
                float4 b = *(const float4*)(eg + k * NE + c0 + 4);
                dot[0] = __fmaf_rn(xv, a.x, dot[0]); dot[1] = __fmaf_rn(xv, a.y, dot[1]);
                dot[2] = __fmaf_rn(xv, a.z, dot[2]); dot[3] = __fmaf_rn(xv, a.w, dot[3]);
                dot[4] = __fmaf_rn(xv, b.x, dot[4]); dot[5] = __fmaf_rn(xv, b.y, dot[5]);
                dot[6] = __fmaf_rn(xv, b.z, dot[6]); dot[7] = __fmaf_rn(xv, b.w, dot[7]);
            }
            float best = 3.4e38f; int bidx = 0;
            #pragma unroll
            for (int j = 0; j < 8; ++j) {
                float d = __fadd_rn(__fmaf_rn(-2.f, dot[j], f2), e2s[c0 + j]);
                if (d < best) { best = d; bidx = c0 + j; }
            }
            #pragma unroll
            for (int m = 1; m < 64; m <<= 1) {
                float ov = __shfl_xor(best, m, 64);
                int   oi = __shfl_xor(bidx, m, 64);
                if (ov < best || (ov == best && oi < bidx)) { best = ov; bidx = oi; }
            }
            int nb = __shfl(bidx, 0, 64);
            if (lane == 0) idxs[p] = nb;
        }
    }
    __syncthreads();

    // hist (striped)
    if (tid < PIXB)
        atomicAdd((unsigned int*)(ws + HIST_OFF) + (blockIdx.x & (NSTRIPE - 1)) * NE + idxs[tid], 1u);

    // apply: float4 re-read of original x; exact ref arithmetic out = x + (q - x); sq loss
    float sq = 0.f;
    for (int t = tid; t < 2048; t += 256) {
        int cc = t >> 5, p4 = (t & 31) << 2;
        float4 vr = *(const float4*)(xg + xbase + (size_t)cc * HWSZ + p4);
        float vv[4] = {vr.x, vr.y, vr.z, vr.w};
        float4 ov;
        float* ovp = &ov.x;
        #pragma unroll
        for (int j = 0; j < 4; ++j) {
            float qv = eg[cc * NE + idxs[p4 + j]];
            float d = __fsub_rn(qv, vv[j]);
            ovp[j] = __fadd_rn(vv[j], d);
            sq = __fmaf_rn(d, d, sq);
        }
        *(float4*)(outg + xbase + (size_t)cc * HWSZ + p4) = ov;
    }
    #pragma unroll
    for (int m = 32; m >= 1; m >>= 1) sq += __shfl_down(sq, m, 64);
    if (lane == 0) wsum[wv] = sq;
    __syncthreads();
    if (tid == 0) atomicAdd((float*)(ws + BATCH_OFF) + bb, wsum[0] + wsum[1] + wsum[2] + wsum[3]);
}

// ---- finalize: sum hist stripes, diff[32], perplexity ----
__global__ __launch_bounds__(512) void vq_fin(const char* __restrict__ ws, float* __restrict__ outg) {
    __shared__ float acc8[8];
    const int tid = threadIdx.x, lane = tid & 63, wv = tid >> 6;
    const unsigned int* h32 = (const unsigned int*)(ws + HIST_OFF);
    unsigned int h = 0;
    #pragma unroll
    for (int s = 0; s < NSTRIPE; ++s) h += h32[s * NE + tid];
    float p = (float)h * (1.f / (float)NPIX);
    float t = p * logf(p + 1e-10f);
    #pragma unroll
    for (int m = 32; m >= 1; m >>= 1) t += __shfl_down(t, m, 64);
    if (lane == 0) acc8[wv] = t;
    __syncthreads();
    if (tid < 32) outg[8388608 + tid] = ((const float*)(ws + BATCH_OFF))[tid] * (1.f / 262144.f);
    if (tid == 0) {
        float s = 0.f;
        #pragma unroll
        for (int u = 0; u < 8; ++u) s += acc8[u];
        outg[8388640] = expf(-s);
    }
}

extern "C" void kernel_launch(void* const* d_in, const int* in_sizes, int n_in,
                              void* d_out, int out_size, void* d_ws, size_t ws_size,
                              hipStream_t stream) {
    const float* xg = (const float*)d_in[0];
    const float* eg = (const float*)d_in[1];
    float* outg = (float*)d_out;
    char* ws = (char*)d_ws;
    vq_init<<<8, 512, 0, stream>>>(eg, ws);
    vq_screen<<<(NPIX / PIXB) * 4, 256, 0, stream>>>(xg, ws);
    vq_apply<<<NPIX / PIXB, 256, 0, stream>>>(xg, eg, outg, ws);
    vq_fin<<<1, 512, 0, stream>>>(ws, outg);
}